// Round 21
// baseline (225.880 us; speedup 1.0000x reference)
//
#include <hip/hip_runtime.h>

// GraphNet forward on MI355X — Round 21: G2/G1 -> 128x256 tile @ 2 blocks/CU.
// Mechanism (m114, HW-measured): co-resident BLOCKS overlap pipes freely;
// barriers only lock waves within a block. The 256^2/128KB-LDS body was
// 1 block/CU -> LDS-read (~1156cy) and MFMA (~1241cy) serialized (~2550cy
// measured). This body: 4 waves, 24KB/K-tile x 3 bufs = 72KB -> 2 blocks/CU,
// same per-CU LDS traffic + MFMA count + swizzle + per-wave frag/epilogue
// (each wave still owns 128x64) -> overlap ceiling ~1300cy/tile.
// Ledger (6 gl_lds/thread/tile, lead 2, 3 bufs): prologue stage 0,1;
// iter t: vmcnt(6) lands t (vmcnt(0) at t=NT-1); barrier; stage(t+2) into
// (t+2)%3=(t-1)%3 (readers done before this barrier); read buf t%3; MFMA.
// Verified for NT=128 (G2) and NT=5 (G1). Accumulation order per output
// element unchanged -> bitwise-identical result. Tail = r20 (validated).
typedef unsigned short u16;
typedef unsigned int u32;
typedef unsigned long long u64;
typedef __bf16 bf16x8 __attribute__((ext_vector_type(8)));
typedef float f32x4 __attribute__((ext_vector_type(4)));

static __device__ __forceinline__ float bf2f(u16 u) {
  return __uint_as_float(((u32)u) << 16);
}
static __device__ __forceinline__ u16 f2bf(float f) {
  u32 x = __float_as_uint(f);
  return (u16)((x + 0x7fffu + ((x >> 16) & 1u)) >> 16);  // RNE
}
static __device__ __forceinline__ void gl_lds16(const u16* g, u16* l) {
  __builtin_amdgcn_global_load_lds(
      (const __attribute__((address_space(1))) void*)g,
      (__attribute__((address_space(3))) void*)l, 16, 0, 0);
}
static __device__ __forceinline__ u64 pack4bf(f32x4 v) {
  u64 r = (u64)f2bf(v[0]);
  r |= (u64)f2bf(v[1]) << 16;
  r |= (u64)f2bf(v[2]) << 32;
  r |= (u64)f2bf(v[3]) << 48;
  return r;
}

// transpose body: f32[K][N] tile at (k0,n0) -> bf16[N][Kpad] (validated r10)
static __device__ __forceinline__ void transpose_tile(const float* in, u16* out,
                                                      int K, int N, int Kpad,
                                                      int k0, int n0, int tid,
                                                      u16* t /*64*68*/) {
#pragma unroll
  for (int pass = 0; pass < 4; pass++) {
    int ki = pass * 16 + (tid >> 4);
    int nj = (tid & 15) * 4;
    f32x4 v = {0.f, 0.f, 0.f, 0.f};
    if (k0 + ki < K) v = *(const f32x4*)&in[(long)(k0 + ki) * N + n0 + nj];
    *(u64*)&t[ki * 68 + nj] = pack4bf(v);
  }
  __syncthreads();
#pragma unroll
  for (int pass = 0; pass < 4; pass++) {
    int ni = pass * 16 + (tid >> 4);
    int kj = (tid & 15) * 4;
    if (k0 + kj < Kpad) {
      u64 w = (u64)t[(kj + 0) * 68 + ni] | ((u64)t[(kj + 1) * 68 + ni] << 16) |
              ((u64)t[(kj + 2) * 68 + ni] << 32) | ((u64)t[(kj + 3) * 68 + ni] << 48);
      *(u64*)&out[(long)(n0 + ni) * Kpad + k0 + kj] = w;
    }
  }
}

// ---------- k_prep: [0,192) eW1T; [192,4288) eW2T; [4288,6848) build_ein ----------
__global__ __launch_bounds__(256) void k_prep(const float* __restrict__ eW1,
                                              u16* __restrict__ eW1T,
                                              const float* __restrict__ eW2,
                                              u16* __restrict__ eW2T,
                                              const float* __restrict__ edges,
                                              const float* __restrict__ nodes,
                                              const float* __restrict__ g,
                                              const int* __restrict__ senders,
                                              const int* __restrict__ receivers,
                                              u16* __restrict__ ein) {
  __shared__ u16 t[64 * 68];
  const int b = blockIdx.x;
  const int tid = threadIdx.x;
  if (b < 192) {
    transpose_tile(eW1, eW1T, 152, 4096, 160, (b % 3) * 64, (b / 3) * 64, tid, t);
    return;
  }
  if (b < 4288) {
    int bb = b - 192;
    transpose_tile(eW2, eW2T, 4096, 4096, 4096, (bb & 63) * 64, (bb >> 6) * 64, tid, t);
    return;
  }
  int idx = (b - 4288) * 256 + tid;  // [0, 655360)
  int e = idx / 160, x = idx - e * 160;
  float v;
  if (x < 16) v = edges[(long)e * 16 + x];
  else if (x < 80) v = nodes[(long)senders[e] * 64 + (x - 16)];
  else if (x < 144) v = nodes[(long)receivers[e] * 64 + (x - 80)];
  else if (x < 152) v = g[x - 144];
  else v = 0.f;
  ein[idx] = f2bf(v);
}

// ---------- k_mid: [0,64) nWmT half0; [64,128) half1; [128,192) zero accb ----------
__global__ __launch_bounds__(256) void k_mid(const float* __restrict__ nW1,
                                             u16* __restrict__ nWmT,
                                             float* __restrict__ accb) {
  __shared__ u16 t[64 * 68];
  const int b = blockIdx.x;
  const int tid = threadIdx.x;
  if (b < 64) {
    transpose_tile(nW1 + 64 * 64, nWmT, 4096, 64, 4096, b * 64, 0, tid, t);
  } else if (b < 128) {
    transpose_tile(nW1 + 4160 * 64, nWmT + (long)64 * 4096, 4096, 64, 4096,
                   (b - 64) * 64, 0, tid, t);
  } else {
    f32x4* a4 = (f32x4*)accb;
    long base = ((long)(b - 128) * 256 + tid) * 8;
#pragma unroll
    for (int j = 0; j < 8; j++) a4[base + j] = {0.f, 0.f, 0.f, 0.f};
  }
}

// ---------- 128x256 MFMA GEMM, 4 waves (1x4), 3-buf, 2 blocks/CU ----------
// MODE 0: C bf16 (G1 -> h). MODE 1: C f32 (G2 -> new_edges).
// grid 1D 512; XCD c owns 4 contiguous A-panels (4MB = its L2).
template <int MODE>
__global__ __launch_bounds__(256, 2) void k_gemm128(const u16* __restrict__ A,
                                                    const u16* __restrict__ BT,
                                                    const float* __restrict__ bias,
                                                    void* __restrict__ C, int N, int K) {
  __shared__ alignas(16) u16 lds[36864];  // 3 bufs x (A 8KB + B 16KB) = 72KB
  const int tid = threadIdx.x;
  const int lane = tid & 63, wc = tid >> 6;  // 4 waves: 1 row x 4 cols
  const int orig = blockIdx.x;
  const int xc = orig & 7, jj = orig >> 3;           // jj in [0,64)
  const int m0 = (4 * xc + (jj >> 4)) * 128;
  const int n0 = (jj & 15) * 256;
  const int lr = lane & 15, lk = lane >> 4;
  const int swz = (lk ^ ((lr >> 1) & 3)) << 3;
  const int NT = K >> 5;

  // stage mapping (verified): issue i covers rows i*64 + (tid>>2); source
  // granule = (tid&3)^((tid>>3)&3) inverts the read swizzle (row>>1)&3.
  const int sq = ((tid & 3) ^ ((tid >> 3) & 3)) << 3;
  const long a_r0 = (long)(m0 + (tid >> 2)) * K + sq;
  const long a_r1 = a_r0 + (long)64 * K;
  const long b_r0 = (long)(n0 + (tid >> 2)) * K + sq;
  const long b_r1 = b_r0 + (long)64 * K;
  const long b_r2 = b_r0 + (long)128 * K;
  const long b_r3 = b_r0 + (long)192 * K;

  f32x4 acc[8][4];
#pragma unroll
  for (int i = 0; i < 8; i++)
#pragma unroll
    for (int j = 0; j < 4; j++) acc[i][j] = {0.f, 0.f, 0.f, 0.f};

#define STAGE_TILE(T, BUF)                          \
  {                                                 \
    const int kt_ = (T) * 32;                       \
    u16* Ab_ = &lds[(BUF) * 12288];                 \
    u16* Bb_ = Ab_ + 4096;                          \
    gl_lds16(&A[a_r0 + kt_], Ab_ + tid * 8);        \
    gl_lds16(&A[a_r1 + kt_], Ab_ + 2048 + tid * 8); \
    gl_lds16(&BT[b_r0 + kt_], Bb_ + tid * 8);       \
    gl_lds16(&BT[b_r1 + kt_], Bb_ + 2048 + tid * 8);\
    gl_lds16(&BT[b_r2 + kt_], Bb_ + 4096 + tid * 8);\
    gl_lds16(&BT[b_r3 + kt_], Bb_ + 6144 + tid * 8);\
  }

  STAGE_TILE(0, 0)
  STAGE_TILE(1, 1)

  int b0 = 0;  // t % 3
  for (int t = 0; t < NT; t++) {
    if (t < NT - 1) {
      asm volatile("s_waitcnt vmcnt(6)" ::: "memory");  // tile t landed
    } else {
      asm volatile("s_waitcnt vmcnt(0)" ::: "memory");
    }
    __builtin_amdgcn_s_barrier();
    if (t + 2 < NT) {
      int sb = b0 ? b0 - 1 : 2;  // (t+2)%3
      STAGE_TILE(t + 2, sb)
    }
    const u16* Ab = &lds[b0 * 12288];
    const u16* Bb = Ab + 4096;
    bf16x8 af[8], bfr[4];
#pragma unroll
    for (int mi = 0; mi < 8; mi++)
      af[mi] = *(const bf16x8*)&Ab[(mi * 16 + lr) * 32 + swz];
#pragma unroll
    for (int ni = 0; ni < 4; ni++)
      bfr[ni] = *(const bf16x8*)&Bb[(wc * 64 + ni * 16 + lr) * 32 + swz];
#pragma unroll
    for (int mi = 0; mi < 8; mi++)
#pragma unroll
      for (int ni = 0; ni < 4; ni++)
        acc[mi][ni] =
            __builtin_amdgcn_mfma_f32_16x16x32_bf16(af[mi], bfr[ni], acc[mi][ni], 0, 0, 0);
    b0 = (b0 == 2) ? 0 : b0 + 1;
  }
#undef STAGE_TILE

#pragma unroll
  for (int ni = 0; ni < 4; ni++) {
    int col = n0 + wc * 64 + ni * 16 + lr;
    float bb = bias[col];
#pragma unroll
    for (int mi = 0; mi < 8; mi++) {
      int row = m0 + mi * 16 + lk * 4;
#pragma unroll
      for (int r = 0; r < 4; r++) {
        float v = fmaxf(acc[mi][ni][r] + bb, 0.f);
        if (MODE == 0) ((u16*)C)[(long)(row + r) * N + col] = f2bf(v);
        else ((float*)C)[(long)(row + r) * N + col] = v;
      }
    }
  }
}

// ---------- MFMA scatter-GEMM: 64-row m-tiles, grid (64,8) (validated r20) ----------
__global__ __launch_bounds__(256) void k_scatter_m(const float* __restrict__ E,
                                                   const u16* __restrict__ BT,
                                                   const int* __restrict__ senders,
                                                   const int* __restrict__ receivers,
                                                   float* __restrict__ accb) {
  const int K = 4096;
  __shared__ alignas(16) u16 As[64 * 32];
  __shared__ alignas(16) u16 Bs[128 * 32];
  const int tid = threadIdx.x;
  const int lane = tid & 63, wc = tid >> 6;
  const int m0 = blockIdx.x * 64;
  const int kbase = blockIdx.y * 512;
  const int lr = lane & 15, lk = lane >> 4;
  const int swz = (lk ^ ((lr >> 1) & 3)) << 3;
  const int srow = tid >> 2;
  const int skk = ((tid & 3) ^ ((tid >> 3) & 3)) << 3;

  f32x4 acc[4][2];
#pragma unroll
  for (int i = 0; i < 4; i++)
#pragma unroll
    for (int j = 0; j < 2; j++) acc[i][j] = {0.f, 0.f, 0.f, 0.f};

  for (int kt = kbase; kt < kbase + 512; kt += 32) {
#pragma unroll
    for (int p = 0; p < 2; p++) {
      int idx = p * 256 + tid;
      int r = idx >> 3;
      int kq = idx & 7;
      f32x4 v = *(const f32x4*)&E[(long)(m0 + r) * 4096 + kt + kq * 4];
      int gq = (kq >> 1) ^ ((r >> 1) & 3);
      *(u64*)&As[r * 32 + gq * 8 + (kq & 1) * 4] = pack4bf(v);
    }
#pragma unroll
    for (int rep = 0; rep < 2; rep++) {
      int row = rep * 64 + srow;
      gl_lds16(&BT[(long)row * K + kt + skk], &Bs[rep * 2048 + tid * 8]);
    }
    __syncthreads();
    bf16x8 af[4], bfr[2];
#pragma unroll
    for (int mi = 0; mi < 4; mi++)
      af[mi] = *(const bf16x8*)&As[(mi * 16 + lr) * 32 + swz];
#pragma unroll
    for (int ni = 0; ni < 2; ni++)
      bfr[ni] = *(const bf16x8*)&Bs[(wc * 32 + ni * 16 + lr) * 32 + swz];
#pragma unroll
    for (int mi = 0; mi < 4; mi++)
#pragma unroll
      for (int ni = 0; ni < 2; ni++)
        acc[mi][ni] =
            __builtin_amdgcn_mfma_f32_16x16x32_bf16(af[mi], bfr[ni], acc[mi][ni], 0, 0, 0);
    __syncthreads();
  }
#pragma unroll
  for (int mi = 0; mi < 4; mi++) {
#pragma unroll
    for (int r = 0; r < 4; r++) {
      int e = m0 + mi * 16 + lk * 4 + r;
#pragma unroll
      for (int ni = 0; ni < 2; ni++) {
        int col = wc * 32 + ni * 16 + lr;
        int tgt = (col < 64) ? senders[e] : receivers[e];
        atomicAdd(&accb[(long)tgt * 64 + (col & 63)], acc[mi][ni][r]);
      }
    }
  }
}

// ---------- final node MLP: 32 nodes/block, grid 256 (validated r20) ----------
__global__ __launch_bounds__(256) void k_final(const float* __restrict__ nodes,
                                               const float* __restrict__ g,
                                               const float* __restrict__ nW1,
                                               const float* __restrict__ nb1,
                                               const float* __restrict__ nW2,
                                               const float* __restrict__ nb2,
                                               const float* __restrict__ zpre,
                                               float* __restrict__ out0) {
  __shared__ float w1[64 * 64];
  __shared__ float w2[64 * 64];
  __shared__ float ns[32 * 64];
  __shared__ float h2[32 * 64];
  __shared__ float gb[64];
  const int tid = threadIdx.x;
  const long n0 = (long)blockIdx.x * 32;
#pragma unroll
  for (int rep = 0; rep < 16; rep++) {
    int idx = rep * 256 + tid;
    w1[idx] = nW1[idx];
    w2[idx] = nW2[idx];
  }
#pragma unroll
  for (int rep = 0; rep < 8; rep++) {
    int idx = rep * 256 + tid;
    ns[idx] = nodes[n0 * 64 + idx];
  }
  if (tid < 64) {
    float s = nb1[tid];
#pragma unroll
    for (int j = 0; j < 8; j++) s += g[j] * nW1[(long)(8256 + j) * 64 + tid];
    gb[tid] = s;
  }
  __syncthreads();
#pragma unroll 2
  for (int rep = 0; rep < 8; rep++) {
    int idx = rep * 256 + tid;
    int i = idx >> 6, c = idx & 63;
    float z = gb[c] + zpre[(n0 + i) * 64 + c];
#pragma unroll 8
    for (int k = 0; k < 64; k++) z += ns[i * 64 + k] * w1[k * 64 + c];
    h2[idx] = fmaxf(z, 0.f);
  }
  __syncthreads();
#pragma unroll 2
  for (int rep = 0; rep < 8; rep++) {
    int idx = rep * 256 + tid;
    int i = idx >> 6, c = idx & 63;
    float z = nb2[c];
#pragma unroll 8
    for (int k = 0; k < 64; k++) z += h2[i * 64 + k] * w2[k * 64 + c];
    out0[(n0 + i) * 64 + c] = fmaxf(z, 0.f);
  }
}

extern "C" void kernel_launch(void* const* d_in, const int* in_sizes, int n_in,
                              void* d_out, int out_size, void* d_ws, size_t ws_size,
                              hipStream_t stream) {
  const float* nodes = (const float*)d_in[0];
  const float* edges = (const float*)d_in[1];
  const float* g = (const float*)d_in[2];
  const int* senders = (const int*)d_in[3];
  const int* receivers = (const int*)d_in[4];
  const float* eW1 = (const float*)d_in[5];
  const float* eb1 = (const float*)d_in[6];
  const float* eW2 = (const float*)d_in[7];
  const float* eb2 = (const float*)d_in[8];
  const float* nW1 = (const float*)d_in[9];
  const float* nb1 = (const float*)d_in[10];
  const float* nW2 = (const float*)d_in[11];
  const float* nb2 = (const float*)d_in[12];

  char* ws = (char*)d_ws;
  u16* eW1T = (u16*)(ws + 0);        // [4096][160] bf16, dies after G1
  float* accb = (float*)(ws + 0);    // [8192][64] f32, zeroed by k_mid (post-G1)
  u16* ein = (u16*)(ws + 2097152);   // [4096][160] bf16, dies after G1
  u16* nWmT = (u16*)(ws + 2097152);  // [128][4096] bf16, written by k_mid
  u16* eW2T = (u16*)(ws + 3407872);  // [4096][4096] bf16
  u16* h = (u16*)(ws + 36962304);    // [4096][4096] bf16 (ends 70.5MB)

  float* out_nodes = (float*)d_out;
  float* out_edges = (float*)d_out + 524288;

  dim3 b256(256);
  k_prep<<<6848, b256, 0, stream>>>(eW1, eW1T, eW2, eW2T, edges, nodes, g,
                                    senders, receivers, ein);
  k_gemm128<0><<<dim3(512), b256, 0, stream>>>(ein, eW1T, eb1, h, 4096, 160);
  k_mid<<<192, b256, 0, stream>>>(nW1, nWmT, accb);
  k_gemm128<1><<<dim3(512), b256, 0, stream>>>(h, eW2T, eb2, out_edges, 4096, 4096);
  k_scatter_m<<<dim3(64, 8), b256, 0, stream>>>(out_edges, nWmT, senders, receivers, accb);
  k_final<<<256, b256, 0, stream>>>(nodes, g, nW1, nb1, nW2, nb2, accb, out_nodes);
}

// Round 22
// 210.089 us; speedup vs baseline: 1.0752x; 1.0752x over previous
//
#include <hip/hip_runtime.h>

// GraphNet forward on MI355X — Round 22: revert to r20 (best measured, 212.8us)
// + ws-gated k_mid merge. r21's 2-blocks/CU regressed (146us, FETCH 147->236MB:
// co-residency cost HBM traffic, bought no overlap). G2 = r9/r11 256^2 body,
// CLOSED at 135us after 5 failed schedule variants (r10/12/13/14/21).
// New: if ws_size >= 73662464, nWmT/accb live at fresh ws (>70.5MB validated
// envelope; gate protects), built inside k_prep (blocks 6848..7040) BEFORE G1
// — legal since they no longer overlay ein/eW1T. Fallback = r20 exact.
typedef unsigned short u16;
typedef unsigned int u32;
typedef unsigned long long u64;
typedef __bf16 bf16x8 __attribute__((ext_vector_type(8)));
typedef float f32x4 __attribute__((ext_vector_type(4)));

static __device__ __forceinline__ float bf2f(u16 u) {
  return __uint_as_float(((u32)u) << 16);
}
static __device__ __forceinline__ u16 f2bf(float f) {
  u32 x = __float_as_uint(f);
  return (u16)((x + 0x7fffu + ((x >> 16) & 1u)) >> 16);  // RNE
}
static __device__ __forceinline__ void gl_lds16(const u16* g, u16* l) {
  __builtin_amdgcn_global_load_lds(
      (const __attribute__((address_space(1))) void*)g,
      (__attribute__((address_space(3))) void*)l, 16, 0, 0);
}
static __device__ __forceinline__ u64 pack4bf(f32x4 v) {
  u64 r = (u64)f2bf(v[0]);
  r |= (u64)f2bf(v[1]) << 16;
  r |= (u64)f2bf(v[2]) << 32;
  r |= (u64)f2bf(v[3]) << 48;
  return r;
}

// transpose body: f32[K][N] tile at (k0,n0) -> bf16[N][Kpad] (validated r10)
static __device__ __forceinline__ void transpose_tile(const float* in, u16* out,
                                                      int K, int N, int Kpad,
                                                      int k0, int n0, int tid,
                                                      u16* t /*64*68*/) {
#pragma unroll
  for (int pass = 0; pass < 4; pass++) {
    int ki = pass * 16 + (tid >> 4);
    int nj = (tid & 15) * 4;
    f32x4 v = {0.f, 0.f, 0.f, 0.f};
    if (k0 + ki < K) v = *(const f32x4*)&in[(long)(k0 + ki) * N + n0 + nj];
    *(u64*)&t[ki * 68 + nj] = pack4bf(v);
  }
  __syncthreads();
#pragma unroll
  for (int pass = 0; pass < 4; pass++) {
    int ni = pass * 16 + (tid >> 4);
    int kj = (tid & 15) * 4;
    if (k0 + kj < Kpad) {
      u64 w = (u64)t[(kj + 0) * 68 + ni] | ((u64)t[(kj + 1) * 68 + ni] << 16) |
              ((u64)t[(kj + 2) * 68 + ni] << 32) | ((u64)t[(kj + 3) * 68 + ni] << 48);
      *(u64*)&out[(long)(n0 + ni) * Kpad + k0 + kj] = w;
    }
  }
}

// ---------- k_prep: [0,192) eW1T; [192,4288) eW2T; [4288,6848) build_ein;
// merged mode only (grid 7040): [6848,6912) nWmT h0; [6912,6976) h1;
// [6976,7040) zero accb ----------
__global__ __launch_bounds__(256) void k_prep(const float* __restrict__ eW1,
                                              u16* __restrict__ eW1T,
                                              const float* __restrict__ eW2,
                                              u16* __restrict__ eW2T,
                                              const float* __restrict__ edges,
                                              const float* __restrict__ nodes,
                                              const float* __restrict__ g,
                                              const int* __restrict__ senders,
                                              const int* __restrict__ receivers,
                                              u16* __restrict__ ein,
                                              const float* __restrict__ nW1,
                                              u16* __restrict__ nWmT,
                                              float* __restrict__ accb) {
  __shared__ u16 t[64 * 68];
  const int b = blockIdx.x;
  const int tid = threadIdx.x;
  if (b < 192) {
    transpose_tile(eW1, eW1T, 152, 4096, 160, (b % 3) * 64, (b / 3) * 64, tid, t);
    return;
  }
  if (b < 4288) {
    int bb = b - 192;
    transpose_tile(eW2, eW2T, 4096, 4096, 4096, (bb & 63) * 64, (bb >> 6) * 64, tid, t);
    return;
  }
  if (b < 6848) {
    int idx = (b - 4288) * 256 + tid;  // [0, 655360)
    int e = idx / 160, x = idx - e * 160;
    float v;
    if (x < 16) v = edges[(long)e * 16 + x];
    else if (x < 80) v = nodes[(long)senders[e] * 64 + (x - 16)];
    else if (x < 144) v = nodes[(long)receivers[e] * 64 + (x - 80)];
    else if (x < 152) v = g[x - 144];
    else v = 0.f;
    ein[idx] = f2bf(v);
    return;
  }
  if (b < 6912) {
    transpose_tile(nW1 + 64 * 64, nWmT, 4096, 64, 4096, (b - 6848) * 64, 0, tid, t);
  } else if (b < 6976) {
    transpose_tile(nW1 + 4160 * 64, nWmT + (long)64 * 4096, 4096, 64, 4096,
                   (b - 6912) * 64, 0, tid, t);
  } else {
    f32x4* a4 = (f32x4*)accb;
    long base = ((long)(b - 6976) * 256 + tid) * 8;
#pragma unroll
    for (int j = 0; j < 8; j++) a4[base + j] = {0.f, 0.f, 0.f, 0.f};
  }
}

// ---------- k_mid (fallback mode only): nWmT + accb zero, post-G1 ----------
__global__ __launch_bounds__(256) void k_mid(const float* __restrict__ nW1,
                                             u16* __restrict__ nWmT,
                                             float* __restrict__ accb) {
  __shared__ u16 t[64 * 68];
  const int b = blockIdx.x;
  const int tid = threadIdx.x;
  if (b < 64) {
    transpose_tile(nW1 + 64 * 64, nWmT, 4096, 64, 4096, b * 64, 0, tid, t);
  } else if (b < 128) {
    transpose_tile(nW1 + 4160 * 64, nWmT + (long)64 * 4096, 4096, 64, 4096,
                   (b - 64) * 64, 0, tid, t);
  } else {
    f32x4* a4 = (f32x4*)accb;
    long base = ((long)(b - 128) * 256 + tid) * 8;
#pragma unroll
    for (int j = 0; j < 8; j++) a4[base + j] = {0.f, 0.f, 0.f, 0.f};
  }
}

// ---------- 256^2 MFMA GEMM (r9/r11 validated schedule + XCD 1D grid) ----------
// MODE 0: C bf16 (G1 -> h). MODE 1: C f32 (G2 -> new_edges).
template <int MODE>
__global__ __launch_bounds__(512, 1) void k_gemm256(const u16* __restrict__ A,
                                                    const u16* __restrict__ BT,
                                                    const float* __restrict__ bias,
                                                    void* __restrict__ C, int N, int K) {
  __shared__ alignas(16) u16 lds[65536];  // 128 KB
  const int tid = threadIdx.x;
  const int lane = tid & 63, wid = tid >> 6;
  const int wr = wid >> 2, wc = wid & 3;
  const int orig = blockIdx.x;
  const int xc = orig & 7, jj = orig >> 3;
  const int m0 = (2 * xc + (jj >> 4)) * 256;
  const int n0 = (jj & 15) * 256;
  const int lr = lane & 15, lk = lane >> 4;
  const int swz = (lk ^ ((lr >> 1) & 3)) << 3;
  const int NT = K >> 5;

  const int srow = wid * 16 + (lane >> 2);
  const int sq = ((lane & 3) ^ ((lane >> 3) & 3)) << 3;
  const int sdst = wid * 512 + lane * 8;

  f32x4 acc[8][4];
#pragma unroll
  for (int i = 0; i < 8; i++)
#pragma unroll
    for (int j = 0; j < 4; j++) acc[i][j] = {0.f, 0.f, 0.f, 0.f};

#define STAGE_TILE(T)                                                              \
  {                                                                                \
    const int kt_ = (T) * 32;                                                      \
    u16* Ab_ = &lds[((T) & 3) * 16384];                                            \
    u16* Bb_ = Ab_ + 8192;                                                         \
    gl_lds16(&A[(long)(m0 + srow) * K + kt_ + sq], Ab_ + sdst);                    \
    gl_lds16(&A[(long)(m0 + 128 + srow) * K + kt_ + sq], Ab_ + 4096 + sdst);       \
    gl_lds16(&BT[(long)(n0 + srow) * K + kt_ + sq], Bb_ + sdst);                   \
    gl_lds16(&BT[(long)(n0 + 128 + srow) * K + kt_ + sq], Bb_ + 4096 + sdst);      \
  }

  STAGE_TILE(0)
  STAGE_TILE(1)
  STAGE_TILE(2)

  for (int t = 0; t < NT; t++) {
    if (t < NT - 2) {
      asm volatile("s_waitcnt vmcnt(8)" ::: "memory");
    } else if (t == NT - 2) {
      asm volatile("s_waitcnt vmcnt(4)" ::: "memory");
    } else {
      asm volatile("s_waitcnt vmcnt(0)" ::: "memory");
    }
    __builtin_amdgcn_s_barrier();
    if (t + 3 < NT) STAGE_TILE(t + 3)

    const u16* Ab = &lds[(t & 3) * 16384];
    const u16* Bb = Ab + 8192;
    bf16x8 af[8], bfr[4];
#pragma unroll
    for (int mi = 0; mi < 8; mi++)
      af[mi] = *(const bf16x8*)&Ab[(wr * 128 + mi * 16 + lr) * 32 + swz];
#pragma unroll
    for (int ni = 0; ni < 4; ni++)
      bfr[ni] = *(const bf16x8*)&Bb[(wc * 64 + ni * 16 + lr) * 32 + swz];
#pragma unroll
    for (int mi = 0; mi < 8; mi++)
#pragma unroll
      for (int ni = 0; ni < 4; ni++)
        acc[mi][ni] =
            __builtin_amdgcn_mfma_f32_16x16x32_bf16(af[mi], bfr[ni], acc[mi][ni], 0, 0, 0);
  }
#undef STAGE_TILE

#pragma unroll
  for (int ni = 0; ni < 4; ni++) {
    int col = n0 + wc * 64 + ni * 16 + lr;
    float bb = bias[col];
#pragma unroll
    for (int mi = 0; mi < 8; mi++) {
      int row = m0 + wr * 128 + mi * 16 + lk * 4;
#pragma unroll
      for (int r = 0; r < 4; r++) {
        float v = fmaxf(acc[mi][ni][r] + bb, 0.f);
        if (MODE == 0) ((u16*)C)[(long)(row + r) * N + col] = f2bf(v);
        else ((float*)C)[(long)(row + r) * N + col] = v;
      }
    }
  }
}

// ---------- MFMA scatter-GEMM: 64-row m-tiles, grid (64,8) (validated r20) ----------
__global__ __launch_bounds__(256) void k_scatter_m(const float* __restrict__ E,
                                                   const u16* __restrict__ BT,
                                                   const int* __restrict__ senders,
                                                   const int* __restrict__ receivers,
                                                   float* __restrict__ accb) {
  const int K = 4096;
  __shared__ alignas(16) u16 As[64 * 32];
  __shared__ alignas(16) u16 Bs[128 * 32];
  const int tid = threadIdx.x;
  const int lane = tid & 63, wc = tid >> 6;
  const int m0 = blockIdx.x * 64;
  const int kbase = blockIdx.y * 512;
  const int lr = lane & 15, lk = lane >> 4;
  const int swz = (lk ^ ((lr >> 1) & 3)) << 3;
  const int srow = tid >> 2;
  const int skk = ((tid & 3) ^ ((tid >> 3) & 3)) << 3;

  f32x4 acc[4][2];
#pragma unroll
  for (int i = 0; i < 4; i++)
#pragma unroll
    for (int j = 0; j < 2; j++) acc[i][j] = {0.f, 0.f, 0.f, 0.f};

  for (int kt = kbase; kt < kbase + 512; kt += 32) {
#pragma unroll
    for (int p = 0; p < 2; p++) {
      int idx = p * 256 + tid;
      int r = idx >> 3;
      int kq = idx & 7;
      f32x4 v = *(const f32x4*)&E[(long)(m0 + r) * 4096 + kt + kq * 4];
      int gq = (kq >> 1) ^ ((r >> 1) & 3);
      *(u64*)&As[r * 32 + gq * 8 + (kq & 1) * 4] = pack4bf(v);
    }
#pragma unroll
    for (int rep = 0; rep < 2; rep++) {
      int row = rep * 64 + srow;
      gl_lds16(&BT[(long)row * K + kt + skk], &Bs[rep * 2048 + tid * 8]);
    }
    __syncthreads();
    bf16x8 af[4], bfr[2];
#pragma unroll
    for (int mi = 0; mi < 4; mi++)
      af[mi] = *(const bf16x8*)&As[(mi * 16 + lr) * 32 + swz];
#pragma unroll
    for (int ni = 0; ni < 2; ni++)
      bfr[ni] = *(const bf16x8*)&Bs[(wc * 32 + ni * 16 + lr) * 32 + swz];
#pragma unroll
    for (int mi = 0; mi < 4; mi++)
#pragma unroll
      for (int ni = 0; ni < 2; ni++)
        acc[mi][ni] =
            __builtin_amdgcn_mfma_f32_16x16x32_bf16(af[mi], bfr[ni], acc[mi][ni], 0, 0, 0);
    __syncthreads();
  }
#pragma unroll
  for (int mi = 0; mi < 4; mi++) {
#pragma unroll
    for (int r = 0; r < 4; r++) {
      int e = m0 + mi * 16 + lk * 4 + r;
#pragma unroll
      for (int ni = 0; ni < 2; ni++) {
        int col = wc * 32 + ni * 16 + lr;
        int tgt = (col < 64) ? senders[e] : receivers[e];
        atomicAdd(&accb[(long)tgt * 64 + (col & 63)], acc[mi][ni][r]);
      }
    }
  }
}

// ---------- final node MLP: 32 nodes/block, grid 256 (validated r20) ----------
__global__ __launch_bounds__(256) void k_final(const float* __restrict__ nodes,
                                               const float* __restrict__ g,
                                               const float* __restrict__ nW1,
                                               const float* __restrict__ nb1,
                                               const float* __restrict__ nW2,
                                               const float* __restrict__ nb2,
                                               const float* __restrict__ zpre,
                                               float* __restrict__ out0) {
  __shared__ float w1[64 * 64];
  __shared__ float w2[64 * 64];
  __shared__ float ns[32 * 64];
  __shared__ float h2[32 * 64];
  __shared__ float gb[64];
  const int tid = threadIdx.x;
  const long n0 = (long)blockIdx.x * 32;
#pragma unroll
  for (int rep = 0; rep < 16; rep++) {
    int idx = rep * 256 + tid;
    w1[idx] = nW1[idx];
    w2[idx] = nW2[idx];
  }
#pragma unroll
  for (int rep = 0; rep < 8; rep++) {
    int idx = rep * 256 + tid;
    ns[idx] = nodes[n0 * 64 + idx];
  }
  if (tid < 64) {
    float s = nb1[tid];
#pragma unroll
    for (int j = 0; j < 8; j++) s += g[j] * nW1[(long)(8256 + j) * 64 + tid];
    gb[tid] = s;
  }
  __syncthreads();
#pragma unroll 2
  for (int rep = 0; rep < 8; rep++) {
    int idx = rep * 256 + tid;
    int i = idx >> 6, c = idx & 63;
    float z = gb[c] + zpre[(n0 + i) * 64 + c];
#pragma unroll 8
    for (int k = 0; k < 64; k++) z += ns[i * 64 + k] * w1[k * 64 + c];
    h2[idx] = fmaxf(z, 0.f);
  }
  __syncthreads();
#pragma unroll 2
  for (int rep = 0; rep < 8; rep++) {
    int idx = rep * 256 + tid;
    int i = idx >> 6, c = idx & 63;
    float z = nb2[c];
#pragma unroll 8
    for (int k = 0; k < 64; k++) z += h2[i * 64 + k] * w2[k * 64 + c];
    out0[(n0 + i) * 64 + c] = fmaxf(z, 0.f);
  }
}

extern "C" void kernel_launch(void* const* d_in, const int* in_sizes, int n_in,
                              void* d_out, int out_size, void* d_ws, size_t ws_size,
                              hipStream_t stream) {
  const float* nodes = (const float*)d_in[0];
  const float* edges = (const float*)d_in[1];
  const float* g = (const float*)d_in[2];
  const int* senders = (const int*)d_in[3];
  const int* receivers = (const int*)d_in[4];
  const float* eW1 = (const float*)d_in[5];
  const float* eb1 = (const float*)d_in[6];
  const float* eW2 = (const float*)d_in[7];
  const float* eb2 = (const float*)d_in[8];
  const float* nW1 = (const float*)d_in[9];
  const float* nb1 = (const float*)d_in[10];
  const float* nW2 = (const float*)d_in[11];
  const float* nb2 = (const float*)d_in[12];

  char* ws = (char*)d_ws;
  u16* eW1T = (u16*)(ws + 0);        // [4096][160] bf16, dies after G1
  u16* ein = (u16*)(ws + 2097152);   // [4096][160] bf16, dies after G1
  u16* eW2T = (u16*)(ws + 3407872);  // [4096][4096] bf16
  u16* h = (u16*)(ws + 36962304);    // [4096][4096] bf16 (ends 70,516,736)

  // merged mode: fresh allocations beyond the 70.5MB validated envelope
  const bool merged = (ws_size >= 73662464ull);
  u16* nWmT;
  float* accb;
  if (merged) {
    nWmT = (u16*)(ws + 70516736);    // 1,048,576 B
    accb = (float*)(ws + 71565312);  // 2,097,152 B (ends 73,662,464)
  } else {
    accb = (float*)(ws + 0);         // overlays dead eW1T (post-G1)
    nWmT = (u16*)(ws + 2097152);     // overlays dead ein  (post-G1)
  }

  float* out_nodes = (float*)d_out;
  float* out_edges = (float*)d_out + 524288;

  dim3 b256(256);
  k_prep<<<merged ? 7040 : 6848, b256, 0, stream>>>(
      eW1, eW1T, eW2, eW2T, edges, nodes, g, senders, receivers, ein, nW1, nWmT, accb);
  k_gemm256<0><<<dim3(256), dim3(512), 0, stream>>>(ein, eW1T, eb1, h, 4096, 160);
  if (!merged) k_mid<<<192, b256, 0, stream>>>(nW1, nWmT, accb);
  k_gemm256<1><<<dim3(256), dim3(512), 0, stream>>>(h, eW2T, eb2, out_edges, 4096, 4096);
  k_scatter_m<<<dim3(64, 8), b256, 0, stream>>>(out_edges, nWmT, senders, receivers, accb);
  k_final<<<256, b256, 0, stream>>>(nodes, g, nW1, nb1, nW2, nb2, accb, out_nodes);
}